// Round 14
// baseline (459.271 us; speedup 1.0000x reference)
//
#include <hip/hip_runtime.h>
#include <hip/hip_bf16.h>

#define TOK 16384   // B*S
#define E 2048
#define DH 128

using bf16x8 = __attribute__((ext_vector_type(8))) __bf16;
using f32x4  = __attribute__((ext_vector_type(4))) float;
using u16x8  = __attribute__((ext_vector_type(8))) unsigned short;

static __device__ __forceinline__ unsigned short f2bf(float f) {
  union { float f; unsigned u; } x; x.f = f;
  unsigned r = x.u + 0x7fffu + ((x.u >> 16) & 1u);   // RNE
  return (unsigned short)(r >> 16);
}

static __device__ __forceinline__ void gload_lds16(const unsigned short* g, unsigned short* l) {
  __builtin_amdgcn_global_load_lds(
      (const __attribute__((address_space(1))) void*)g,
      (__attribute__((address_space(3))) void*)l, 16, 0, 0);
}

// ---------------- unified prep kernel (one launch) ----------------
static __device__ __forceinline__ void cvt8(const float* __restrict__ src,
                                            unsigned short* __restrict__ dst,
                                            float sc) {
  const float4* p = reinterpret_cast<const float4*>(src);
  float4 v0 = p[0], v1 = p[1];
  u16x8 o;
  o[0] = f2bf(v0.x * sc); o[1] = f2bf(v0.y * sc); o[2] = f2bf(v0.z * sc); o[3] = f2bf(v0.w * sc);
  o[4] = f2bf(v1.x * sc); o[5] = f2bf(v1.y * sc); o[6] = f2bf(v1.z * sc); o[7] = f2bf(v1.w * sc);
  *reinterpret_cast<u16x8*>(dst) = o;
}

__global__ __launch_bounds__(256) void prep_all(const float* __restrict__ x,
                                                const float* __restrict__ Wz,
                                                const float* __restrict__ Wx,
                                                const float* __restrict__ Wo,
                                                const float* __restrict__ bz,
                                                const float* __restrict__ bx,
                                                const float* __restrict__ phase,
                                                unsigned short* __restrict__ x_bf,
                                                unsigned short* __restrict__ wzx,
                                                unsigned short* __restrict__ wo_bf,
                                                float* __restrict__ bzx) {
  const int N0 = TOK * E / 8;   // x groups
  const int N1 = E * E / 8;     // per-weight groups
  const int NB = (2 * E) / 8;   // bias groups
  const float rs = 0.08838834764831845f;  // 1/sqrt(128)
  const int total = N0 + 3 * N1 + NB;
  const int stride = gridDim.x * blockDim.x;
  for (int i = blockIdx.x * blockDim.x + threadIdx.x; i < total; i += stride) {
    if (i < N0) {
      cvt8(x + (size_t)i * 8, x_bf + (size_t)i * 8, 1.0f);
    } else if (i < N0 + N1) {
      const int j = i - N0;
      const float sc = sinf(phase[j >> 8]) * rs;   // row = (j*8)/2048
      cvt8(Wz + (size_t)j * 8, wzx + (size_t)j * 8, sc);
    } else if (i < N0 + 2 * N1) {
      const int j = i - N0 - N1;
      cvt8(Wx + (size_t)j * 8, wzx + (size_t)E * E + (size_t)j * 8, 1.0f);
    } else if (i < N0 + 3 * N1) {
      const int j = i - N0 - 2 * N1;
      cvt8(Wo + (size_t)j * 8, wo_bf + (size_t)j * 8, 1.0f);
    } else {
      const int j = i - N0 - 3 * N1;
#pragma unroll
      for (int k = 0; k < 8; ++k) {
        const int idx = j * 8 + k;
        bzx[idx] = (idx < E) ? bz[idx] * sinf(phase[idx]) * rs : bx[idx - E];
      }
    }
  }
}

// ---------------- 256x256 GEMM: 1 barrier / K-tile, B triple-buffered ----------------
#define MFMA16 __builtin_amdgcn_mfma_f32_16x16x32_bf16

// swizzled LDS fragment read: slot ^= row&7  (slot = 16B unit, 8 per 128B row)
static __device__ __forceinline__ bf16x8 ldf(const unsigned short* buf, int row, int slot) {
  return *reinterpret_cast<const bf16x8*>(buf + row * 64 + ((slot ^ (row & 7)) << 3));
}

// stage one 128-row half-tile: 2 x global_load_lds(16B) per thread.
static __device__ __forceinline__ void stage_half(const unsigned short* gbase, int ld,
                                                  unsigned short* dsthalf,
                                                  int r, int slot, int wave) {
#pragma unroll
  for (int c = 0; c < 2; ++c)
    gload_lds16(gbase + (size_t)(c * 64 + r) * ld + slot * 8,
                dsthalf + c * 4096 + wave * 512);
}

static __device__ __forceinline__ void quad(f32x4 (&acc)[8][4], const bf16x8 (&a)[4][2],
                                            const bf16x8 (&b)[2][2], int mh, int nh) {
#pragma unroll
  for (int mi = 0; mi < 4; ++mi)
#pragma unroll
    for (int ni = 0; ni < 2; ++ni)
#pragma unroll
      for (int kk = 0; kk < 2; ++kk)
        acc[mh * 4 + mi][nh * 2 + ni] =
            MFMA16(a[mi][kk], b[ni][kk], acc[mh * 4 + mi][nh * 2 + ni], 0, 0, 0);
}

#define PH_BAR()  __builtin_amdgcn_s_barrier()
#define VMCNT(n)  asm volatile("s_waitcnt vmcnt(" #n ")" ::: "memory")
#define PRIO1()   __builtin_amdgcn_s_setprio(1)
#define PRIO0()   __builtin_amdgcn_s_setprio(0)

#define LD_A(dst, buf, base)                                             \
  _Pragma("unroll")                                                      \
  for (int mi = 0; mi < 4; ++mi)                                         \
    _Pragma("unroll")                                                    \
    for (int kk = 0; kk < 2; ++kk)                                       \
      dst[mi][kk] = ldf(buf, (base) + mi * 16, kk * 4 + grp);

#define LD_B(dst, buf, base)                                             \
  _Pragma("unroll")                                                      \
  for (int ni = 0; ni < 2; ++ni)                                         \
    _Pragma("unroll")                                                    \
    for (int kk = 0; kk < 2; ++kk)                                       \
      dst[ni][kk] = ldf(buf, (base) + ni * 16, kk * 4 + grp);

// One window per K-tile t: reads {A(t)=pa0, B(t)=pb0}; stages {A(t+1)->pa1,
// B(t+2)->pb2} — disjoint buffers, so NO intra-window hazard; 1 vmcnt + 1
// barrier per tile. Steady-state proof: entering t, outstanding={B(t+1):4};
// window issues A(t+1):4 then B(t+2):4 -> 12; vmcnt(4) proves B(t+1)+A(t+1),
// leaves B(t+2) in flight. Overwrite safety: staged buffers' last reads were
// MFMA-consumed (ds_read retired) before bar(t-1). Tail: t=NT-2 -> vmcnt(0);
// t=NT-1 computes only.
template <bool OUT_BF16>
__global__ __launch_bounds__(512, 2) void gemm256(const unsigned short* __restrict__ A,
                                                  const unsigned short* __restrict__ Bm,
                                                  const float* __restrict__ bias,
                                                  void* __restrict__ C,
                                                  int M, int N, int K_, int lda) {
  extern __shared__ unsigned short lds[];

  const int nbn = N >> 8;
  const int bid = blockIdx.x;
  const int swz = (bid & 7) * ((int)gridDim.x >> 3) + (bid >> 3);  // XCD swizzle (nwg%8==0)
  const int by = swz / nbn, bx = swz % nbn;
  const int tm = by << 8, tn = bx << 8;

  const int tid = threadIdx.x;
  const int wave = tid >> 6, lane = tid & 63;
  const int g16 = lane & 15, grp = lane >> 4;
  const int wm = wave >> 2, wn = wave & 3;
  const int rA = wm * 128 + g16;
  const int rB = wn * 64 + g16;
  const int r = tid >> 3;
  const int slot = (tid & 7) ^ ((tid >> 3) & 7);

  const unsigned short* Ag = A + (size_t)tm * lda;
  const unsigned short* Bg = Bm + (size_t)tn * K_;
  const size_t hA = (size_t)128 * lda, hB = (size_t)128 * K_;

  f32x4 acc[8][4];
#pragma unroll
  for (int i = 0; i < 8; ++i)
#pragma unroll
    for (int j = 0; j < 4; ++j) acc[i][j] = (f32x4){0.f, 0.f, 0.f, 0.f};

  unsigned short* pa0 = lds;            // A(t)     (256x64 = 16384 elems)
  unsigned short* pa1 = lds + 16384;    // A stage
  unsigned short* pb0 = lds + 32768;    // B(t)
  unsigned short* pb1 = lds + 49152;    // B(t+1)
  unsigned short* pb2 = lds + 65536;    // B stage (t+2)

  // prologue: A(0), B(0), B(1) = 12 loads/thread; vmcnt(4) leaves B(1) flying
  stage_half(Ag, lda, pa0, r, slot, wave);
  stage_half(Ag + hA, lda, pa0 + 8192, r, slot, wave);
  stage_half(Bg, K_, pb0, r, slot, wave);
  stage_half(Bg + hB, K_, pb0 + 8192, r, slot, wave);
  stage_half(Bg + 64, K_, pb1, r, slot, wave);
  stage_half(Bg + hB + 64, K_, pb1 + 8192, r, slot, wave);
  VMCNT(4);
  __builtin_amdgcn_s_barrier();

  const int NT = K_ >> 6;  // K-tiles of 64
#pragma unroll 1
  for (int t = 0; t < NT; ++t) {
    bf16x8 aF[4][2], b0F[2][2], b1F[2][2];

    LD_A(aF, pa0, rA);                       // A(t).mh0
    LD_B(b0F, pb0, rB);                      // B(t).nh0
    if (t + 1 < NT) {
      const size_t k1 = (size_t)(t + 1) * 64;
      stage_half(Ag + k1, lda, pa1, r, slot, wave);
      stage_half(Ag + hA + k1, lda, pa1 + 8192, r, slot, wave);
    }
    PRIO1(); quad(acc, aF, b0F, 0, 0); PRIO0();

    LD_B(b1F, pb0, rB + 32);                 // B(t).nh1
    if (t + 2 < NT) {
      const size_t k2 = (size_t)(t + 2) * 64;
      stage_half(Bg + k2, K_, pb2, r, slot, wave);
      stage_half(Bg + hB + k2, K_, pb2 + 8192, r, slot, wave);
    }
    PRIO1(); quad(acc, aF, b1F, 0, 1); PRIO0();

    LD_A(aF, pa0, rA + 64);                  // A(t).mh1 (reuse regs)
    PRIO1(); quad(acc, aF, b1F, 1, 1); PRIO0();
    PRIO1(); quad(acc, aF, b0F, 1, 0); PRIO0();

    if (t + 2 < NT)      { VMCNT(4); PH_BAR(); }
    else if (t + 1 < NT) { VMCNT(0); PH_BAR(); }
    // rotate buffers
    unsigned short* tA = pa0; pa0 = pa1; pa1 = tA;
    unsigned short* tB = pb0; pb0 = pb1; pb1 = pb2; pb2 = tB;
  }

  // epilogue: 16x16 C/D layout: row = (lane>>4)*4 + j, col = lane&15
#pragma unroll
  for (int mi = 0; mi < 8; ++mi) {
#pragma unroll
    for (int ni = 0; ni < 4; ++ni) {
      const int row = tm + wm * 128 + mi * 16 + grp * 4;
      const int col = tn + wn * 64 + ni * 16 + g16;
      const float bv = bias[col];
#pragma unroll
      for (int j = 0; j < 4; ++j) {
        const float v = acc[mi][ni][j] + bv;
        if (OUT_BF16)
          ((unsigned short*)C)[(size_t)(row + j) * N + col] = f2bf(v);
        else
          ((float*)C)[(size_t)(row + j) * N + col] = v;
      }
    }
  }
}

// ---------------- per-token head-mixing attention ----------------
// reads z|xs from C12 (stride 4096), writes att DENSE into attq (stride 2048)
__global__ __launch_bounds__(512) void attn_kernel(const unsigned short* __restrict__ zc,
                                                   unsigned short* __restrict__ attq) {
  __shared__ __align__(16) unsigned short xs_lds[8][16][136];
  __shared__ float w_lds[8][16][17];

  const int wave = threadIdx.x >> 6, lane = threadIdx.x & 63;
  const int token = (blockIdx.x << 3) | wave;
  const unsigned short* modp = zc + (size_t)token * (2 * E);   // mod cols 0..2047
  const unsigned short* xsp  = modp + E;                       // xs cols 2048..4095
  const int g16 = lane & 15, grp = lane >> 4;

  bf16x8 a[4], b[4];
#pragma unroll
  for (int kk = 0; kk < 4; ++kk) {
    a[kk] = *reinterpret_cast<const bf16x8*>(modp + g16 * DH + kk * 32 + grp * 8);
    b[kk] = *reinterpret_cast<const bf16x8*>(xsp  + g16 * DH + kk * 32 + grp * 8);
  }
#pragma unroll
  for (int kk = 0; kk < 4; ++kk)
    *reinterpret_cast<bf16x8*>(&xs_lds[wave][g16][kk * 32 + grp * 8]) = b[kk];

  f32x4 sc = (f32x4){0.f, 0.f, 0.f, 0.f};
#pragma unroll
  for (int kk = 0; kk < 4; ++kk)
    sc = MFMA16(a[kk], b[kk], sc, 0, 0, 0);

  float w4[4];
#pragma unroll
  for (int j = 0; j < 4; ++j) {
    float s = sc[j];
    float m = s;
#pragma unroll
    for (int off = 1; off < 16; off <<= 1) m = fmaxf(m, __shfl_xor(m, off));
    float e = __expf(s - m);
    float t = e;
#pragma unroll
    for (int off = 1; off < 16; off <<= 1) t += __shfl_xor(t, off);
    w4[j] = e / t;
  }
#pragma unroll
  for (int j = 0; j < 4; ++j) w_lds[wave][grp * 4 + j][g16] = w4[j];

  __syncthreads();

  float acc[32];
#pragma unroll
  for (int i = 0; i < 32; ++i) acc[i] = 0.f;
#pragma unroll
  for (int g = 0; g < 16; ++g) {
    const float wg = w_lds[wave][g16][g];
#pragma unroll
    for (int c = 0; c < 4; ++c) {
      bf16x8 xv = *reinterpret_cast<const bf16x8*>(&xs_lds[wave][g][grp * 32 + c * 8]);
#pragma unroll
      for (int j = 0; j < 8; ++j) acc[c * 8 + j] += wg * (float)xv[j];
    }
  }

  unsigned short* op = attq + (size_t)token * E + g16 * DH + grp * 32;  // dense
#pragma unroll
  for (int c = 0; c < 4; ++c) {
    u16x8 o;
#pragma unroll
    for (int j = 0; j < 8; ++j) o[j] = f2bf(acc[c * 8 + j]);
    *reinterpret_cast<u16x8*>(op + c * 8) = o;
  }
}

// ---------------- launch ----------------
extern "C" void kernel_launch(void* const* d_in, const int* in_sizes, int n_in,
                              void* d_out, int out_size, void* d_ws, size_t ws_size,
                              hipStream_t stream) {
  const float* x     = (const float*)d_in[0];
  const float* Wz    = (const float*)d_in[1];
  const float* bz    = (const float*)d_in[2];
  const float* Wx    = (const float*)d_in[3];
  const float* bx    = (const float*)d_in[4];
  const float* phase = (const float*)d_in[5];
  const float* Wo    = (const float*)d_in[6];
  const float* bo    = (const float*)d_in[7];

  char* p = (char*)d_ws;
  unsigned short* x_bf  = (unsigned short*)p; p += (size_t)TOK * E * 2;      // x, then att (reuse)
  unsigned short* C12   = (unsigned short*)p; p += (size_t)TOK * 2 * E * 2;  // [TOK][4096]
  unsigned short* wzx   = (unsigned short*)p; p += (size_t)2 * E * E * 2;    // [4096][2048]
  unsigned short* wo_bf = (unsigned short*)p; p += (size_t)E * E * 2;
  float* bzx            = (float*)p;          p += (size_t)2 * E * 4;

  hipFuncSetAttribute((const void*)gemm256<true>,
                      hipFuncAttributeMaxDynamicSharedMemorySize, 163840);
  hipFuncSetAttribute((const void*)gemm256<false>,
                      hipFuncAttributeMaxDynamicSharedMemorySize, 163840);

  prep_all<<<2048, 256, 0, stream>>>(x, Wz, Wx, Wo, bz, bx, phase, x_bf, wzx, wo_bf, bzx);

  // fused z|xs GEMM: [TOK,2048] @ [4096,2048]^T -> [TOK,4096]
  gemm256<true><<<dim3((TOK / 256) * (2 * E / 256)), 512, 163840, stream>>>(
      x_bf, wzx, bzx, C12, TOK, 2 * E, E, E);
  // attn: C12 -> dense att into x_bf (x_bf is dead after the fused GEMM)
  attn_kernel<<<TOK / 8, 512, 0, stream>>>(C12, x_bf);
  // out GEMM: att (dense, lda=2048) @ Wo^T -> d_out fp32
  gemm256<false><<<dim3((TOK / 256) * (E / 256)), 512, 163840, stream>>>(
      x_bf, wo_bf, bo, (float*)d_out, TOK, E, E, E);
}

// Round 15
// 454.921 us; speedup vs baseline: 1.0096x; 1.0096x over previous
//
#include <hip/hip_runtime.h>
#include <hip/hip_bf16.h>

#define TOK 16384   // B*S
#define E 2048
#define DH 128

using bf16x8 = __attribute__((ext_vector_type(8))) __bf16;
using f32x4  = __attribute__((ext_vector_type(4))) float;
using u16x8  = __attribute__((ext_vector_type(8))) unsigned short;

static __device__ __forceinline__ unsigned short f2bf(float f) {
  union { float f; unsigned u; } x; x.f = f;
  unsigned r = x.u + 0x7fffu + ((x.u >> 16) & 1u);   // RNE
  return (unsigned short)(r >> 16);
}

static __device__ __forceinline__ void gload_lds16(const unsigned short* g, unsigned short* l) {
  __builtin_amdgcn_global_load_lds(
      (const __attribute__((address_space(1))) void*)g,
      (__attribute__((address_space(3))) void*)l, 16, 0, 0);
}

// ---------------- unified prep kernel (one launch) ----------------
static __device__ __forceinline__ void cvt8(const float* __restrict__ src,
                                            unsigned short* __restrict__ dst,
                                            float sc) {
  const float4* p = reinterpret_cast<const float4*>(src);
  float4 v0 = p[0], v1 = p[1];
  u16x8 o;
  o[0] = f2bf(v0.x * sc); o[1] = f2bf(v0.y * sc); o[2] = f2bf(v0.z * sc); o[3] = f2bf(v0.w * sc);
  o[4] = f2bf(v1.x * sc); o[5] = f2bf(v1.y * sc); o[6] = f2bf(v1.z * sc); o[7] = f2bf(v1.w * sc);
  *reinterpret_cast<u16x8*>(dst) = o;
}

__global__ __launch_bounds__(256) void prep_all(const float* __restrict__ x,
                                                const float* __restrict__ Wz,
                                                const float* __restrict__ Wx,
                                                const float* __restrict__ Wo,
                                                const float* __restrict__ bz,
                                                const float* __restrict__ bx,
                                                const float* __restrict__ phase,
                                                unsigned short* __restrict__ x_bf,
                                                unsigned short* __restrict__ wzx,
                                                unsigned short* __restrict__ wo_bf,
                                                float* __restrict__ bzx) {
  const int N0 = TOK * E / 8;   // x groups
  const int N1 = E * E / 8;     // per-weight groups
  const int NB = (2 * E) / 8;   // bias groups
  const float rs = 0.08838834764831845f;  // 1/sqrt(128)
  const int total = N0 + 3 * N1 + NB;
  const int stride = gridDim.x * blockDim.x;
  for (int i = blockIdx.x * blockDim.x + threadIdx.x; i < total; i += stride) {
    if (i < N0) {
      cvt8(x + (size_t)i * 8, x_bf + (size_t)i * 8, 1.0f);
    } else if (i < N0 + N1) {
      const int j = i - N0;
      const float sc = sinf(phase[j >> 8]) * rs;   // row = (j*8)/2048
      cvt8(Wz + (size_t)j * 8, wzx + (size_t)j * 8, sc);
    } else if (i < N0 + 2 * N1) {
      const int j = i - N0 - N1;
      cvt8(Wx + (size_t)j * 8, wzx + (size_t)E * E + (size_t)j * 8, 1.0f);
    } else if (i < N0 + 3 * N1) {
      const int j = i - N0 - 2 * N1;
      cvt8(Wo + (size_t)j * 8, wo_bf + (size_t)j * 8, 1.0f);
    } else {
      const int j = i - N0 - 3 * N1;
#pragma unroll
      for (int k = 0; k < 8; ++k) {
        const int idx = j * 8 + k;
        bzx[idx] = (idx < E) ? bz[idx] * sinf(phase[idx]) * rs : bx[idx - E];
      }
    }
  }
}

// ---------------- 256x256 GEMM, 4-barrier drift schedule (R10-proven) ----------------
#define MFMA16 __builtin_amdgcn_mfma_f32_16x16x32_bf16

// swizzled LDS fragment read: slot ^= row&7  (slot = 16B unit, 8 per 128B row)
static __device__ __forceinline__ bf16x8 ldf(const unsigned short* buf, int row, int slot) {
  return *reinterpret_cast<const bf16x8*>(buf + row * 64 + ((slot ^ (row & 7)) << 3));
}

// stage one 128-row half-tile: 2 x global_load_lds(16B) per thread.
static __device__ __forceinline__ void stage_half(const unsigned short* gbase, int ld,
                                                  unsigned short* dsthalf,
                                                  int r, int slot, int wave) {
#pragma unroll
  for (int c = 0; c < 2; ++c)
    gload_lds16(gbase + (size_t)(c * 64 + r) * ld + slot * 8,
                dsthalf + c * 4096 + wave * 512);
}

static __device__ __forceinline__ void quad(f32x4 (&acc)[8][4], const bf16x8 (&a)[4][2],
                                            const bf16x8 (&b)[2][2], int mh, int nh) {
#pragma unroll
  for (int mi = 0; mi < 4; ++mi)
#pragma unroll
    for (int ni = 0; ni < 2; ++ni)
#pragma unroll
      for (int kk = 0; kk < 2; ++kk)
        acc[mh * 4 + mi][nh * 2 + ni] =
            MFMA16(a[mi][kk], b[ni][kk], acc[mh * 4 + mi][nh * 2 + ni], 0, 0, 0);
}

#define PH_BAR()  __builtin_amdgcn_s_barrier()
#define VMCNT(n)  asm volatile("s_waitcnt vmcnt(" #n ")" ::: "memory")
#define PRIO1()   __builtin_amdgcn_s_setprio(1)
#define PRIO0()   __builtin_amdgcn_s_setprio(0)

#define LD_A(dst, buf, base)                                             \
  _Pragma("unroll")                                                      \
  for (int mi = 0; mi < 4; ++mi)                                         \
    _Pragma("unroll")                                                    \
    for (int kk = 0; kk < 2; ++kk)                                       \
      dst[mi][kk] = ldf(buf, (base) + mi * 16, kk * 4 + grp);

#define LD_B(dst, buf, base)                                             \
  _Pragma("unroll")                                                      \
  for (int ni = 0; ni < 2; ++ni)                                         \
    _Pragma("unroll")                                                    \
    for (int kk = 0; kk < 2; ++kk)                                       \
      dst[ni][kk] = ldf(buf, (base) + ni * 16, kk * 4 + grp);

// 4-barrier k_iter: phase pairs, one vmcnt+BAR per pair (R10; see R10 notes).
template <bool LAST>
static __device__ __forceinline__ void k_iter(
    const unsigned short* __restrict__ Ag, const unsigned short* __restrict__ Bg,
    int K_, int lda, int t,
    unsigned short* sA0, unsigned short* sA1, unsigned short* sB0, unsigned short* sB1,
    int r, int slot, int wave, int grp, int rA, int rB,
    bf16x8 (&bP)[2][2], bf16x8 (&bQ)[2][2], f32x4 (&acc)[8][4]) {
  const size_t k1 = (size_t)(t + 1) * 64, k2 = (size_t)(t + 2) * 64, k3 = (size_t)(t + 3) * 64;
  const size_t hA = (size_t)128 * lda, hB = (size_t)128 * K_;
  bf16x8 aF[4][2], b1F[2][2];

  // ---- pair A (tile t, quads (0,0),(0,1)) ; stage A(t+1) -> sA1
  LD_A(aF, sA0, rA);
  stage_half(Ag + k1, lda, sA1, r, slot, wave);
  PRIO1(); quad(acc, aF, bP, 0, 0); PRIO0();
  LD_B(b1F, sB0, rB + 32);
  stage_half(Ag + hA + k1, lda, sA1 + 8192, r, slot, wave);
  PRIO1(); quad(acc, aF, b1F, 0, 1); PRIO0();
  VMCNT(4);   // proves B(t+1) (staged prev pair D)
  PH_BAR();

  // ---- pair B (tile t, quads (1,1),(1,0)) ; stage B(t+2) -> sB0
  LD_A(aF, sA0, rA + 64);
  if (!LAST) stage_half(Bg + k2, K_, sB0, r, slot, wave);
  PRIO1(); quad(acc, aF, b1F, 1, 1); PRIO0();
  LD_B(bQ, sB1, rB);                       // B(t+1).nh0 — proven at BAR_a
  if (!LAST) stage_half(Bg + hB + k2, K_, sB0 + 8192, r, slot, wave);
  PRIO1(); quad(acc, aF, bP, 1, 0); PRIO0();
  if (!LAST) { VMCNT(4); } else { VMCNT(0); }   // proves A(t+1)
  PH_BAR();

  // ---- pair C (tile t+1, quads (0,0),(0,1)) ; stage A(t+2) -> sA0
  LD_A(aF, sA1, rA);
  if (!LAST) stage_half(Ag + k2, lda, sA0, r, slot, wave);
  PRIO1(); quad(acc, aF, bQ, 0, 0); PRIO0();
  LD_B(b1F, sB1, rB + 32);
  if (!LAST) stage_half(Ag + hA + k2, lda, sA0 + 8192, r, slot, wave);
  PRIO1(); quad(acc, aF, b1F, 0, 1); PRIO0();
  if (!LAST) { VMCNT(4); }                 // proves B(t+2)
  PH_BAR();

  // ---- pair D (tile t+1, quads (1,1),(1,0)) ; stage B(t+3) -> sB1
  LD_A(aF, sA1, rA + 64);
  if (!LAST) stage_half(Bg + k3, K_, sB1, r, slot, wave);
  PRIO1(); quad(acc, aF, b1F, 1, 1); PRIO0();
  if (!LAST) {
    LD_B(bP, sB0, rB);                     // B(t+2).nh0 — proven at BAR_c
    stage_half(Bg + hB + k3, K_, sB1 + 8192, r, slot, wave);
  }
  PRIO1(); quad(acc, aF, bQ, 1, 0); PRIO0();
  if (!LAST) { VMCNT(4); }                 // proves A(t+2)
  PH_BAR();
}

template <bool OUT_BF16>
__global__ __launch_bounds__(512, 2) void gemm256(const unsigned short* __restrict__ A,
                                                  const unsigned short* __restrict__ Bm,
                                                  const float* __restrict__ bias,
                                                  void* __restrict__ C,
                                                  int M, int N, int K_, int lda) {
  extern __shared__ unsigned short lds[];
  unsigned short* sA0 = lds;
  unsigned short* sA1 = lds + 16384;
  unsigned short* sB0 = lds + 32768;
  unsigned short* sB1 = lds + 49152;

  const int nbn = N >> 8;
  const int bid = blockIdx.x;
  const int swz = (bid & 7) * ((int)gridDim.x >> 3) + (bid >> 3);  // XCD swizzle (nwg%8==0)
  const int by = swz / nbn, bx = swz % nbn;
  const int tm = by << 8, tn = bx << 8;

  const int tid = threadIdx.x;
  const int wave = tid >> 6, lane = tid & 63;
  const int g16 = lane & 15, grp = lane >> 4;
  const int wm = wave >> 2, wn = wave & 3;
  const int rA = wm * 128 + g16;
  const int rB = wn * 64 + g16;
  const int r = tid >> 3;
  const int slot = (tid & 7) ^ ((tid >> 3) & 7);

  const unsigned short* Ag = A + (size_t)tm * lda;
  const unsigned short* Bg = Bm + (size_t)tn * K_;
  const size_t hA = (size_t)128 * lda, hB = (size_t)128 * K_;

  f32x4 acc[8][4];
#pragma unroll
  for (int i = 0; i < 8; ++i)
#pragma unroll
    for (int j = 0; j < 4; ++j) acc[i][j] = (f32x4){0.f, 0.f, 0.f, 0.f};

  bf16x8 bP[2][2], bQ[2][2];

  // prologue: t0.A, t0.B, t1.B = 12 loads/thread
  stage_half(Ag, lda, sA0, r, slot, wave);
  stage_half(Ag + hA, lda, sA0 + 8192, r, slot, wave);
  stage_half(Bg, K_, sB0, r, slot, wave);
  stage_half(Bg + hB, K_, sB0 + 8192, r, slot, wave);
  stage_half(Bg + 64, K_, sB1, r, slot, wave);
  stage_half(Bg + hB + 64, K_, sB1 + 8192, r, slot, wave);
  VMCNT(4);                      // A(t0),B(t0) proven; B(t1) in flight
  __builtin_amdgcn_s_barrier();
  LD_B(bP, sB0, rB);             // B(t0).nh0 ; drained by ph1 MFMA operand waits

  const int NI = K_ >> 7;  // 2 K-tiles per iteration
#pragma unroll 1
  for (int i = 0; i < NI - 1; ++i)
    k_iter<false>(Ag, Bg, K_, lda, 2 * i, sA0, sA1, sB0, sB1, r, slot, wave, grp, rA, rB,
                  bP, bQ, acc);
  k_iter<true>(Ag, Bg, K_, lda, 2 * (NI - 1), sA0, sA1, sB0, sB1, r, slot, wave, grp, rA, rB,
               bP, bQ, acc);

  // epilogue: 16x16 C/D layout: row = (lane>>4)*4 + j, col = lane&15
#pragma unroll
  for (int mi = 0; mi < 8; ++mi) {
#pragma unroll
    for (int ni = 0; ni < 4; ++ni) {
      const int row = tm + wm * 128 + mi * 16 + grp * 4;
      const int col = tn + wn * 64 + ni * 16 + g16;
      const float bv = bias[col];
#pragma unroll
      for (int j = 0; j < 4; ++j) {
        const float v = acc[mi][ni][j] + bv;
        if (OUT_BF16)
          ((unsigned short*)C)[(size_t)(row + j) * N + col] = f2bf(v);
        else
          ((float*)C)[(size_t)(row + j) * N + col] = v;
      }
    }
  }
}

// ---------------- per-token head-mixing attention ----------------
// reads z|xs from C12 (stride 4096), writes att DENSE into attq (stride 2048)
__global__ __launch_bounds__(512) void attn_kernel(const unsigned short* __restrict__ zc,
                                                   unsigned short* __restrict__ attq) {
  __shared__ __align__(16) unsigned short xs_lds[8][16][136];
  __shared__ float w_lds[8][16][17];

  const int wave = threadIdx.x >> 6, lane = threadIdx.x & 63;
  const int token = (blockIdx.x << 3) | wave;
  const unsigned short* modp = zc + (size_t)token * (2 * E);   // mod cols 0..2047
  const unsigned short* xsp  = modp + E;                       // xs cols 2048..4095
  const int g16 = lane & 15, grp = lane >> 4;

  bf16x8 a[4], b[4];
#pragma unroll
  for (int kk = 0; kk < 4; ++kk) {
    a[kk] = *reinterpret_cast<const bf16x8*>(modp + g16 * DH + kk * 32 + grp * 8);
    b[kk] = *reinterpret_cast<const bf16x8*>(xsp  + g16 * DH + kk * 32 + grp * 8);
  }
#pragma unroll
  for (int kk = 0; kk < 4; ++kk)
    *reinterpret_cast<bf16x8*>(&xs_lds[wave][g16][kk * 32 + grp * 8]) = b[kk];

  f32x4 sc = (f32x4){0.f, 0.f, 0.f, 0.f};
#pragma unroll
  for (int kk = 0; kk < 4; ++kk)
    sc = MFMA16(a[kk], b[kk], sc, 0, 0, 0);

  float w4[4];
#pragma unroll
  for (int j = 0; j < 4; ++j) {
    float s = sc[j];
    float m = s;
#pragma unroll
    for (int off = 1; off < 16; off <<= 1) m = fmaxf(m, __shfl_xor(m, off));
    float e = __expf(s - m);
    float t = e;
#pragma unroll
    for (int off = 1; off < 16; off <<= 1) t += __shfl_xor(t, off);
    w4[j] = e / t;
  }
#pragma unroll
  for (int j = 0; j < 4; ++j) w_lds[wave][grp * 4 + j][g16] = w4[j];

  __syncthreads();

  float acc[32];
#pragma unroll
  for (int i = 0; i < 32; ++i) acc[i] = 0.f;
#pragma unroll
  for (int g = 0; g < 16; ++g) {
    const float wg = w_lds[wave][g16][g];
#pragma unroll
    for (int c = 0; c < 4; ++c) {
      bf16x8 xv = *reinterpret_cast<const bf16x8*>(&xs_lds[wave][g][grp * 32 + c * 8]);
#pragma unroll
      for (int j = 0; j < 8; ++j) acc[c * 8 + j] += wg * (float)xv[j];
    }
  }

  unsigned short* op = attq + (size_t)token * E + g16 * DH + grp * 32;  // dense
#pragma unroll
  for (int c = 0; c < 4; ++c) {
    u16x8 o;
#pragma unroll
    for (int j = 0; j < 8; ++j) o[j] = f2bf(acc[c * 8 + j]);
    *reinterpret_cast<u16x8*>(op + c * 8) = o;
  }
}

// ---------------- launch ----------------
extern "C" void kernel_launch(void* const* d_in, const int* in_sizes, int n_in,
                              void* d_out, int out_size, void* d_ws, size_t ws_size,
                              hipStream_t stream) {
  const float* x     = (const float*)d_in[0];
  const float* Wz    = (const float*)d_in[1];
  const float* bz    = (const float*)d_in[2];
  const float* Wx    = (const float*)d_in[3];
  const float* bx    = (const float*)d_in[4];
  const float* phase = (const float*)d_in[5];
  const float* Wo    = (const float*)d_in[6];
  const float* bo    = (const float*)d_in[7];

  char* p = (char*)d_ws;
  unsigned short* x_bf  = (unsigned short*)p; p += (size_t)TOK * E * 2;      // x, then att (reuse)
  unsigned short* C12   = (unsigned short*)p; p += (size_t)TOK * 2 * E * 2;  // [TOK][4096]
  unsigned short* wzx   = (unsigned short*)p; p += (size_t)2 * E * E * 2;    // [4096][2048]
  unsigned short* wo_bf = (unsigned short*)p; p += (size_t)E * E * 2;
  float* bzx            = (float*)p;          p += (size_t)2 * E * 4;

  hipFuncSetAttribute((const void*)gemm256<true>,
                      hipFuncAttributeMaxDynamicSharedMemorySize, 131072);
  hipFuncSetAttribute((const void*)gemm256<false>,
                      hipFuncAttributeMaxDynamicSharedMemorySize, 131072);

  prep_all<<<2048, 256, 0, stream>>>(x, Wz, Wx, Wo, bz, bx, phase, x_bf, wzx, wo_bf, bzx);

  // fused z|xs GEMM: [TOK,2048] @ [4096,2048]^T -> [TOK,4096]
  gemm256<true><<<dim3((TOK / 256) * (2 * E / 256)), 512, 131072, stream>>>(
      x_bf, wzx, bzx, C12, TOK, 2 * E, E, E);
  // attn: C12 -> dense att into x_bf (x_bf is dead after the fused GEMM)
  attn_kernel<<<TOK / 8, 512, 0, stream>>>(C12, x_bf);
  // out GEMM: att (dense, lda=2048) @ Wo^T -> d_out fp32
  gemm256<false><<<dim3((TOK / 256) * (E / 256)), 512, 131072, stream>>>(
      x_bf, wo_bf, bo, (float*)d_out, TOK, E, E, E);
}

// Round 16
// 453.783 us; speedup vs baseline: 1.0121x; 1.0025x over previous
//
#include <hip/hip_runtime.h>
#include <hip/hip_bf16.h>

#define TOK 16384   // B*S
#define E 2048
#define DH 128

using bf16x8 = __attribute__((ext_vector_type(8))) __bf16;
using f32x4  = __attribute__((ext_vector_type(4))) float;
using u16x8  = __attribute__((ext_vector_type(8))) unsigned short;

static __device__ __forceinline__ unsigned short f2bf(float f) {
  union { float f; unsigned u; } x; x.f = f;
  unsigned r = x.u + 0x7fffu + ((x.u >> 16) & 1u);   // RNE
  return (unsigned short)(r >> 16);
}

static __device__ __forceinline__ void gload_lds16(const unsigned short* g, unsigned short* l) {
  __builtin_amdgcn_global_load_lds(
      (const __attribute__((address_space(1))) void*)g,
      (__attribute__((address_space(3))) void*)l, 16, 0, 0);
}

// ---------------- unified prep kernel (one launch) ----------------
static __device__ __forceinline__ void cvt8(const float* __restrict__ src,
                                            unsigned short* __restrict__ dst,
                                            float sc) {
  const float4* p = reinterpret_cast<const float4*>(src);
  float4 v0 = p[0], v1 = p[1];
  u16x8 o;
  o[0] = f2bf(v0.x * sc); o[1] = f2bf(v0.y * sc); o[2] = f2bf(v0.z * sc); o[3] = f2bf(v0.w * sc);
  o[4] = f2bf(v1.x * sc); o[5] = f2bf(v1.y * sc); o[6] = f2bf(v1.z * sc); o[7] = f2bf(v1.w * sc);
  *reinterpret_cast<u16x8*>(dst) = o;
}

__global__ __launch_bounds__(256) void prep_all(const float* __restrict__ x,
                                                const float* __restrict__ Wz,
                                                const float* __restrict__ Wx,
                                                const float* __restrict__ Wo,
                                                const float* __restrict__ bz,
                                                const float* __restrict__ bx,
                                                const float* __restrict__ phase,
                                                unsigned short* __restrict__ x_bf,
                                                unsigned short* __restrict__ wzx,
                                                unsigned short* __restrict__ wo_bf,
                                                float* __restrict__ bzx) {
  const int N0 = TOK * E / 8;   // x groups
  const int N1 = E * E / 8;     // per-weight groups
  const int NB = (2 * E) / 8;   // bias groups
  const float rs = 0.08838834764831845f;  // 1/sqrt(128)
  const int total = N0 + 3 * N1 + NB;
  const int stride = gridDim.x * blockDim.x;
  for (int i = blockIdx.x * blockDim.x + threadIdx.x; i < total; i += stride) {
    if (i < N0) {
      cvt8(x + (size_t)i * 8, x_bf + (size_t)i * 8, 1.0f);
    } else if (i < N0 + N1) {
      const int j = i - N0;
      const float sc = sinf(phase[j >> 8]) * rs;   // row = (j*8)/2048
      cvt8(Wz + (size_t)j * 8, wzx + (size_t)j * 8, sc);
    } else if (i < N0 + 2 * N1) {
      const int j = i - N0 - N1;
      cvt8(Wx + (size_t)j * 8, wzx + (size_t)E * E + (size_t)j * 8, 1.0f);
    } else if (i < N0 + 3 * N1) {
      const int j = i - N0 - 2 * N1;
      cvt8(Wo + (size_t)j * 8, wo_bf + (size_t)j * 8, 1.0f);
    } else {
      const int j = i - N0 - 3 * N1;
#pragma unroll
      for (int k = 0; k < 8; ++k) {
        const int idx = j * 8 + k;
        bzx[idx] = (idx < E) ? bz[idx] * sinf(phase[idx]) * rs : bx[idx - E];
      }
    }
  }
}

// ---------------- 256x256 GEMM, 4-barrier drift schedule (R10-proven) ----------------
#define MFMA16 __builtin_amdgcn_mfma_f32_16x16x32_bf16

// swizzled LDS fragment read: slot ^= row&7  (slot = 16B unit, 8 per 128B row)
static __device__ __forceinline__ bf16x8 ldf(const unsigned short* buf, int row, int slot) {
  return *reinterpret_cast<const bf16x8*>(buf + row * 64 + ((slot ^ (row & 7)) << 3));
}

// stage one 128-row half-tile: 2 x global_load_lds(16B) per thread.
static __device__ __forceinline__ void stage_half(const unsigned short* gbase, int ld,
                                                  unsigned short* dsthalf,
                                                  int r, int slot, int wave) {
#pragma unroll
  for (int c = 0; c < 2; ++c)
    gload_lds16(gbase + (size_t)(c * 64 + r) * ld + slot * 8,
                dsthalf + c * 4096 + wave * 512);
}

static __device__ __forceinline__ void quad(f32x4 (&acc)[8][4], const bf16x8 (&a)[4][2],
                                            const bf16x8 (&b)[2][2], int mh, int nh) {
#pragma unroll
  for (int mi = 0; mi < 4; ++mi)
#pragma unroll
    for (int ni = 0; ni < 2; ++ni)
#pragma unroll
      for (int kk = 0; kk < 2; ++kk)
        acc[mh * 4 + mi][nh * 2 + ni] =
            MFMA16(a[mi][kk], b[ni][kk], acc[mh * 4 + mi][nh * 2 + ni], 0, 0, 0);
}

#define PH_BAR()  __builtin_amdgcn_s_barrier()
#define VMCNT(n)  asm volatile("s_waitcnt vmcnt(" #n ")" ::: "memory")
#define PRIO1()   __builtin_amdgcn_s_setprio(1)
#define PRIO0()   __builtin_amdgcn_s_setprio(0)

#define LD_A(dst, buf, base)                                             \
  _Pragma("unroll")                                                      \
  for (int mi = 0; mi < 4; ++mi)                                         \
    _Pragma("unroll")                                                    \
    for (int kk = 0; kk < 2; ++kk)                                       \
      dst[mi][kk] = ldf(buf, (base) + mi * 16, kk * 4 + grp);

#define LD_B(dst, buf, base)                                             \
  _Pragma("unroll")                                                      \
  for (int ni = 0; ni < 2; ++ni)                                         \
    _Pragma("unroll")                                                    \
    for (int kk = 0; kk < 2; ++kk)                                       \
      dst[ni][kk] = ldf(buf, (base) + ni * 16, kk * 4 + grp);

// 4-barrier k_iter: phase pairs {1,2}{3,4}{5,6}{7,8}, one vmcnt(4)+BAR per pair.
// Each pair's STAGE target buffer is disjoint from that pair's READS; vmcnt(4)
// before each barrier proves the 4 oldest loads (staged 2 windows earlier).
template <bool LAST>
static __device__ __forceinline__ void k_iter(
    const unsigned short* __restrict__ Ag, const unsigned short* __restrict__ Bg,
    int K_, int lda, int t,
    unsigned short* sA0, unsigned short* sA1, unsigned short* sB0, unsigned short* sB1,
    int r, int slot, int wave, int grp, int rA, int rB,
    bf16x8 (&bP)[2][2], bf16x8 (&bQ)[2][2], f32x4 (&acc)[8][4]) {
  const size_t k1 = (size_t)(t + 1) * 64, k2 = (size_t)(t + 2) * 64, k3 = (size_t)(t + 3) * 64;
  const size_t hA = (size_t)128 * lda, hB = (size_t)128 * K_;
  bf16x8 aF[4][2], b1F[2][2];

  // ---- pair A (tile t, quads (0,0),(0,1)) ; stage A(t+1) -> sA1
  LD_A(aF, sA0, rA);
  stage_half(Ag + k1, lda, sA1, r, slot, wave);
  PRIO1(); quad(acc, aF, bP, 0, 0); PRIO0();
  LD_B(b1F, sB0, rB + 32);
  stage_half(Ag + hA + k1, lda, sA1 + 8192, r, slot, wave);
  PRIO1(); quad(acc, aF, b1F, 0, 1); PRIO0();
  VMCNT(4);   // proves B(t+1) (staged prev pair D)
  PH_BAR();

  // ---- pair B (tile t, quads (1,1),(1,0)) ; stage B(t+2) -> sB0
  LD_A(aF, sA0, rA + 64);
  if (!LAST) stage_half(Bg + k2, K_, sB0, r, slot, wave);
  PRIO1(); quad(acc, aF, b1F, 1, 1); PRIO0();
  LD_B(bQ, sB1, rB);                       // B(t+1).nh0 — proven at BAR_a
  if (!LAST) stage_half(Bg + hB + k2, K_, sB0 + 8192, r, slot, wave);
  PRIO1(); quad(acc, aF, bP, 1, 0); PRIO0();
  if (!LAST) { VMCNT(4); } else { VMCNT(0); }   // proves A(t+1)
  PH_BAR();

  // ---- pair C (tile t+1, quads (0,0),(0,1)) ; stage A(t+2) -> sA0
  LD_A(aF, sA1, rA);
  if (!LAST) stage_half(Ag + k2, lda, sA0, r, slot, wave);
  PRIO1(); quad(acc, aF, bQ, 0, 0); PRIO0();
  LD_B(b1F, sB1, rB + 32);
  if (!LAST) stage_half(Ag + hA + k2, lda, sA0 + 8192, r, slot, wave);
  PRIO1(); quad(acc, aF, b1F, 0, 1); PRIO0();
  if (!LAST) { VMCNT(4); }                 // proves B(t+2)
  PH_BAR();

  // ---- pair D (tile t+1, quads (1,1),(1,0)) ; stage B(t+3) -> sB1
  LD_A(aF, sA1, rA + 64);
  if (!LAST) stage_half(Bg + k3, K_, sB1, r, slot, wave);
  PRIO1(); quad(acc, aF, b1F, 1, 1); PRIO0();
  if (!LAST) {
    LD_B(bP, sB0, rB);                     // B(t+2).nh0 — proven at BAR_c
    stage_half(Bg + hB + k3, K_, sB1 + 8192, r, slot, wave);
  }
  PRIO1(); quad(acc, aF, bQ, 1, 0); PRIO0();
  if (!LAST) { VMCNT(4); }                 // proves A(t+2)
  PH_BAR();
}

template <bool OUT_BF16>
__global__ __launch_bounds__(512, 2) void gemm256(const unsigned short* __restrict__ A,
                                                  const unsigned short* __restrict__ Bm,
                                                  const float* __restrict__ bias,
                                                  void* __restrict__ C,
                                                  int M, int N, int K_, int lda) {
  extern __shared__ unsigned short lds[];
  unsigned short* sA0 = lds;
  unsigned short* sA1 = lds + 16384;
  unsigned short* sB0 = lds + 32768;
  unsigned short* sB1 = lds + 49152;

  const int nbn = N >> 8;
  const int bid = blockIdx.x;
  const int swz = (bid & 7) * ((int)gridDim.x >> 3) + (bid >> 3);  // XCD swizzle (nwg%8==0)
  const int by = swz / nbn, bx = swz % nbn;
  const int tm = by << 8, tn = bx << 8;

  const int tid = threadIdx.x;
  const int wave = tid >> 6, lane = tid & 63;
  const int g16 = lane & 15, grp = lane >> 4;
  const int wm = wave >> 2, wn = wave & 3;
  const int rA = wm * 128 + g16;
  const int rB = wn * 64 + g16;
  const int r = tid >> 3;
  const int slot = (tid & 7) ^ ((tid >> 3) & 7);

  const unsigned short* Ag = A + (size_t)tm * lda;
  const unsigned short* Bg = Bm + (size_t)tn * K_;
  const size_t hA = (size_t)128 * lda, hB = (size_t)128 * K_;

  f32x4 acc[8][4];
#pragma unroll
  for (int i = 0; i < 8; ++i)
#pragma unroll
    for (int j = 0; j < 4; ++j) acc[i][j] = (f32x4){0.f, 0.f, 0.f, 0.f};

  bf16x8 bP[2][2], bQ[2][2];

  // prologue: t0.A, t0.B, t1.B = 12 loads/thread
  stage_half(Ag, lda, sA0, r, slot, wave);
  stage_half(Ag + hA, lda, sA0 + 8192, r, slot, wave);
  stage_half(Bg, K_, sB0, r, slot, wave);
  stage_half(Bg + hB, K_, sB0 + 8192, r, slot, wave);
  stage_half(Bg + 64, K_, sB1, r, slot, wave);
  stage_half(Bg + hB + 64, K_, sB1 + 8192, r, slot, wave);
  VMCNT(4);                      // A(t0),B(t0) proven; B(t1) in flight
  __builtin_amdgcn_s_barrier();
  LD_B(bP, sB0, rB);             // B(t0).nh0 ; drained by ph1 MFMA operand waits

  const int NI = K_ >> 7;  // 2 K-tiles per iteration
#pragma unroll 1
  for (int i = 0; i < NI - 1; ++i)
    k_iter<false>(Ag, Bg, K_, lda, 2 * i, sA0, sA1, sB0, sB1, r, slot, wave, grp, rA, rB,
                  bP, bQ, acc);
  k_iter<true>(Ag, Bg, K_, lda, 2 * (NI - 1), sA0, sA1, sB0, sB1, r, slot, wave, grp, rA, rB,
               bP, bQ, acc);

  // epilogue: 16x16 C/D layout: row = (lane>>4)*4 + j, col = lane&15
#pragma unroll
  for (int mi = 0; mi < 8; ++mi) {
#pragma unroll
    for (int ni = 0; ni < 4; ++ni) {
      const int row = tm + wm * 128 + mi * 16 + grp * 4;
      const int col = tn + wn * 64 + ni * 16 + g16;
      const float bv = bias[col];
#pragma unroll
      for (int j = 0; j < 4; ++j) {
        const float v = acc[mi][ni][j] + bv;
        if (OUT_BF16)
          ((unsigned short*)C)[(size_t)(row + j) * N + col] = f2bf(v);
        else
          ((float*)C)[(size_t)(row + j) * N + col] = v;
      }
    }
  }
}

// ---------------- per-token head-mixing attention ----------------
// reads z|xs from C12 (stride 4096), writes att DENSE into attq (stride 2048)
__global__ __launch_bounds__(512) void attn_kernel(const unsigned short* __restrict__ zc,
                                                   unsigned short* __restrict__ attq) {
  __shared__ __align__(16) unsigned short xs_lds[8][16][136];
  __shared__ float w_lds[8][16][17];

  const int wave = threadIdx.x >> 6, lane = threadIdx.x & 63;
  const int token = (blockIdx.x << 3) | wave;
  const unsigned short* modp = zc + (size_t)token * (2 * E);   // mod cols 0..2047
  const unsigned short* xsp  = modp + E;                       // xs cols 2048..4095
  const int g16 = lane & 15, grp = lane >> 4;

  bf16x8 a[4], b[4];
#pragma unroll
  for (int kk = 0; kk < 4; ++kk) {
    a[kk] = *reinterpret_cast<const bf16x8*>(modp + g16 * DH + kk * 32 + grp * 8);
    b[kk] = *reinterpret_cast<const bf16x8*>(xsp  + g16 * DH + kk * 32 + grp * 8);
  }
#pragma unroll
  for (int kk = 0; kk < 4; ++kk)
    *reinterpret_cast<bf16x8*>(&xs_lds[wave][g16][kk * 32 + grp * 8]) = b[kk];

  f32x4 sc = (f32x4){0.f, 0.f, 0.f, 0.f};
#pragma unroll
  for (int kk = 0; kk < 4; ++kk)
    sc = MFMA16(a[kk], b[kk], sc, 0, 0, 0);

  float w4[4];
#pragma unroll
  for (int j = 0; j < 4; ++j) {
    float s = sc[j];
    float m = s;
#pragma unroll
    for (int off = 1; off < 16; off <<= 1) m = fmaxf(m, __shfl_xor(m, off));
    float e = __expf(s - m);
    float t = e;
#pragma unroll
    for (int off = 1; off < 16; off <<= 1) t += __shfl_xor(t, off);
    w4[j] = e / t;
  }
#pragma unroll
  for (int j = 0; j < 4; ++j) w_lds[wave][grp * 4 + j][g16] = w4[j];

  __syncthreads();

  float acc[32];
#pragma unroll
  for (int i = 0; i < 32; ++i) acc[i] = 0.f;
#pragma unroll
  for (int g = 0; g < 16; ++g) {
    const float wg = w_lds[wave][g16][g];
#pragma unroll
    for (int c = 0; c < 4; ++c) {
      bf16x8 xv = *reinterpret_cast<const bf16x8*>(&xs_lds[wave][g][grp * 32 + c * 8]);
#pragma unroll
      for (int j = 0; j < 8; ++j) acc[c * 8 + j] += wg * (float)xv[j];
    }
  }

  unsigned short* op = attq + (size_t)token * E + g16 * DH + grp * 32;  // dense
#pragma unroll
  for (int c = 0; c < 4; ++c) {
    u16x8 o;
#pragma unroll
    for (int j = 0; j < 8; ++j) o[j] = f2bf(acc[c * 8 + j]);
    *reinterpret_cast<u16x8*>(op + c * 8) = o;
  }
}

// ---------------- launch ----------------
extern "C" void kernel_launch(void* const* d_in, const int* in_sizes, int n_in,
                              void* d_out, int out_size, void* d_ws, size_t ws_size,
                              hipStream_t stream) {
  const float* x     = (const float*)d_in[0];
  const float* Wz    = (const float*)d_in[1];
  const float* bz    = (const float*)d_in[2];
  const float* Wx    = (const float*)d_in[3];
  const float* bx    = (const float*)d_in[4];
  const float* phase = (const float*)d_in[5];
  const float* Wo    = (const float*)d_in[6];
  const float* bo    = (const float*)d_in[7];

  char* p = (char*)d_ws;
  unsigned short* x_bf  = (unsigned short*)p; p += (size_t)TOK * E * 2;      // x, then att (reuse)
  unsigned short* C12   = (unsigned short*)p; p += (size_t)TOK * 2 * E * 2;  // [TOK][4096]
  unsigned short* wzx   = (unsigned short*)p; p += (size_t)2 * E * E * 2;    // [4096][2048]
  unsigned short* wo_bf = (unsigned short*)p; p += (size_t)E * E * 2;
  float* bzx            = (float*)p;          p += (size_t)2 * E * 4;

  hipFuncSetAttribute((const void*)gemm256<true>,
                      hipFuncAttributeMaxDynamicSharedMemorySize, 131072);
  hipFuncSetAttribute((const void*)gemm256<false>,
                      hipFuncAttributeMaxDynamicSharedMemorySize, 131072);

  prep_all<<<2048, 256, 0, stream>>>(x, Wz, Wx, Wo, bz, bx, phase, x_bf, wzx, wo_bf, bzx);

  // fused z|xs GEMM: [TOK,2048] @ [4096,2048]^T -> [TOK,4096]
  gemm256<true><<<dim3((TOK / 256) * (2 * E / 256)), 512, 131072, stream>>>(
      x_bf, wzx, bzx, C12, TOK, 2 * E, E, E);
  // attn: C12 -> dense att into x_bf (x_bf is dead after the fused GEMM)
  attn_kernel<<<TOK / 8, 512, 0, stream>>>(C12, x_bf);
  // out GEMM: att (dense, lda=2048) @ Wo^T -> d_out fp32
  gemm256<false><<<dim3((TOK / 256) * (E / 256)), 512, 131072, stream>>>(
      x_bf, wo_bf, bo, (float*)d_out, TOK, E, E, E);
}